// Round 9
// baseline (25240.930 us; speedup 1.0000x reference)
//
#include <hip/hip_runtime.h>
#include <hip/hip_bf16.h>
#include <hip/hip_cooperative_groups.h>

namespace cg = cooperative_groups;

#define CB 256      // batch
#define CN 256      // nodes
#define CK 3        // children per node
#define CE 256      // embedding dim
#define CH 256      // hidden dim
#define CG_ 1536    // gates = 6*CH
#define KTOT 1024   // E + K*H
#define APAD 8
#define ASTR (KTOT + APAD)   // LDS A row stride (shorts) = 1032 (2064 B)

typedef __attribute__((ext_vector_type(8))) short short8v;          // 8 bf16
typedef __attribute__((ext_vector_type(4))) float float4v;          // MFMA C/D
typedef __attribute__((ext_vector_type(4))) unsigned int uint4v;    // 16B copy
typedef __attribute__((ext_vector_type(4))) unsigned short ushort4v;// 8B store

__device__ __forceinline__ unsigned short f2bfu(float v) {
    __hip_bfloat16 h = __float2bfloat16(v);
    return __builtin_bit_cast(unsigned short, h);
}
__device__ __forceinline__ float bfu2f(unsigned short u) {
    __hip_bfloat16 h = __builtin_bit_cast(__hip_bfloat16, u);
    return __bfloat162float(h);
}

// ---------------------------------------------------------------------------
// Prep (verified r8): split virtual W = [Wx_w ; Uh_w] (1024 x 1536) into
// K-major bf16 hi/lo planes [g][k] -> B-fragments are contiguous 16B loads.
// ---------------------------------------------------------------------------
__global__ __launch_bounds__(256) void prep_w(
    const float* __restrict__ Wx_w, const float* __restrict__ Uh_w,
    unsigned short* __restrict__ Whi, unsigned short* __restrict__ Wlo)
{
    const int g = blockIdx.x;
    for (int k = threadIdx.x; k < KTOT; k += 256) {
        float w = (k < CE) ? Wx_w[(size_t)k * CG_ + g]
                           : Uh_w[(size_t)(k - CE) * CG_ + g];
        unsigned short hi = f2bfu(w);
        Whi[(size_t)g * KTOT + k] = hi;
        Wlo[(size_t)g * KTOT + k] = f2bfu(w - bfu2f(hi));
    }
}

// ---------------------------------------------------------------------------
// Cooperative scan, MFMA bf16x3. 256 blocks x 768 threads (12 waves).
// Block (bi,hi) owns (16 batch x 16 hidden). h history stored as bf16 hi/lo
// planes (split at write time) so staging is pure 16B copies; x split
// in-register from fp32 emb. Waves: np=wv%3 (N-pair), kq=wv/3 (K-quarter,
// 8 k-iters). Coop grid.sync per step (structure behaviorally verified
// rounds 2-4: bit-identical to per-step launches).
// MFMA 16x16x32 layouts (verified r8): A lane l: row=l&15, k=(l>>4)*8+j;
// B lane l: col=l&15, same k; D lane l: col=l&15, row=(l>>4)*4+reg.
// ---------------------------------------------------------------------------
__global__ __launch_bounds__(768) void tree_scan_mfma(
    const int* __restrict__ node_ids,          // [B][N]
    const int* __restrict__ children,          // [B][N][K]
    const float* __restrict__ emb,             // [V][E]
    const unsigned short* __restrict__ Whi,    // [1536][1024]
    const unsigned short* __restrict__ Wlo,    // [1536][1024]
    const float* __restrict__ Wx_b,            // [G]
    const float* __restrict__ Uh_b,            // [K][G]
    unsigned short* __restrict__ h_hi,         // [N][B][H] bf16 hi plane
    unsigned short* __restrict__ h_lo,         // [N][B][H] bf16 lo plane
    float* __restrict__ c_s,                   // [N][B][H] f32
    float* __restrict__ out)                   // [B][H] f32
{
    cg::grid_group grid = cg::this_grid();
    const int tid = threadIdx.x;

    const int xcd  = blockIdx.x & 7;
    const int bidx = blockIdx.x >> 3;
    const int hi   = xcd * 2 + (bidx & 1);
    const int bi   = bidx >> 1;
    const int b0   = bi * 16;
    const int hh0  = hi * 16;

    __shared__ unsigned short Ahi[16][ASTR];   // 33,024 B
    __shared__ unsigned short Alo[16][ASTR];   // 33,024 B
    __shared__ float part[4][6][16][16];       // 24,576 B  [kq][q][bb][jj]
    __shared__ int   nid[16];
    __shared__ float msk[16][3];
    __shared__ int   cix[16][3];

    const int wv    = tid >> 6;                // 0..11
    const int l     = tid & 63;
    const int np    = wv % 3;                  // N-pair
    const int kq    = wv / 3;                  // K-quarter
    const int lan15 = l & 15;
    const int k8    = (l >> 4) * 8;

    for (int t = 0; t < CN; ++t) {
        if (tid < 16) nid[tid] = node_ids[(size_t)(b0 + tid) * CN + t];
        if (tid < 48) {
            int lb = tid / 3, k = tid - lb * 3;
            int raw = children[((size_t)(b0 + lb) * CN + t) * CK + k];
            int v = raw < t;
            msk[lb][k] = v ? 1.0f : 0.0f;
            cix[lb][k] = v ? raw : 0;
        }
        __syncthreads();

        // stage x: 16 rows x 64 float4 chunks; split hi/lo in-register
        for (int idx = tid; idx < 1024; idx += 768) {
            int lb = idx >> 6, c4 = idx & 63;
            float4v v = *(const float4v*)(emb + (size_t)nid[lb] * CE + c4 * 4);
            ushort4v h4, l4;
            #pragma unroll
            for (int j = 0; j < 4; ++j) {
                unsigned short hb = f2bfu(v[j]);
                h4[j] = hb;
                l4[j] = f2bfu(v[j] - bfu2f(hb));
            }
            *(ushort4v*)&Ahi[lb][c4 * 4] = h4;
            *(ushort4v*)&Alo[lb][c4 * 4] = l4;
        }
        // stage h: 48 rows x (32 hi + 32 lo) 16B chunks = 3072 copies
        for (int idx = tid; idx < 3072; idx += 768) {
            int r  = idx >> 6;                 // 0..47
            int c  = idx & 63;
            int pl = c >> 5;                   // 0=hi, 1=lo
            int ch = c & 31;                   // 16B chunk in row
            int lb = r / 3, k = r - lb * 3;
            uint4v val = (uint4v){0u, 0u, 0u, 0u};
            if (msk[lb][k] != 0.0f) {
                const unsigned short* src = (pl ? h_lo : h_hi)
                    + ((size_t)cix[lb][k] * CB + (b0 + lb)) * CH + ch * 8;
                val = *(const uint4v*)src;
            }
            unsigned short* dst = (pl ? &Alo[lb][CE + k * CH + ch * 8]
                                      : &Ahi[lb][CE + k * CH + ch * 8]);
            *(uint4v*)dst = val;
        }
        __syncthreads();

        // MFMA bf16x3: 8 k-iters per wave, 2 q-tiles, 3 chains
        {
            float4v acc[2][3];
            #pragma unroll
            for (int a = 0; a < 2; ++a)
                #pragma unroll
                for (int b = 0; b < 3; ++b)
                    acc[a][b] = (float4v){0.f, 0.f, 0.f, 0.f};

            #pragma unroll
            for (int ci = 0; ci < 8; ++ci) {
                const int kb = (kq * 8 + ci) * 32 + k8;
                short8v ahi = *(const short8v*)&Ahi[lan15][kb];
                short8v alo = *(const short8v*)&Alo[lan15][kb];
                #pragma unroll
                for (int t2 = 0; t2 < 2; ++t2) {
                    const size_t gcol = (size_t)((np * 2 + t2) * CH + hh0 + lan15);
                    short8v bhi = *(const short8v*)(Whi + gcol * KTOT + kb);
                    short8v blo = *(const short8v*)(Wlo + gcol * KTOT + kb);
                    acc[t2][0] = __builtin_amdgcn_mfma_f32_16x16x32_bf16(ahi, bhi, acc[t2][0], 0, 0, 0);
                    acc[t2][1] = __builtin_amdgcn_mfma_f32_16x16x32_bf16(ahi, blo, acc[t2][1], 0, 0, 0);
                    acc[t2][2] = __builtin_amdgcn_mfma_f32_16x16x32_bf16(alo, bhi, acc[t2][2], 0, 0, 0);
                }
            }
            #pragma unroll
            for (int t2 = 0; t2 < 2; ++t2)
                #pragma unroll
                for (int r = 0; r < 4; ++r)
                    part[kq][np * 2 + t2][(l >> 4) * 4 + r][lan15] =
                        acc[t2][0][r] + acc[t2][1][r] + acc[t2][2][r];
        }
        __syncthreads();

        // cell phase (r7-verified math; h written pre-split)
        if (tid < 256) {
            const int bb = tid >> 4, j2 = tid & 15;
            const int b = b0 + bb, hh = hh0 + j2;
            const float m0 = msk[bb][0], m1 = msk[bb][1], m2 = msk[bb][2];
            float g[6];
            #pragma unroll
            for (int q = 0; q < 6; ++q) {
                int gc = q * CH + hh;
                g[q] = part[0][q][bb][j2] + part[1][q][bb][j2]
                     + part[2][q][bb][j2] + part[3][q][bb][j2]
                     + Wx_b[gc] + m0 * Uh_b[gc] + m1 * Uh_b[CG_ + gc]
                                + m2 * Uh_b[2 * CG_ + gc];
            }
            float ig = 1.0f / (1.0f + expf(-g[0]));
            float og = 1.0f / (1.0f + expf(-g[1]));
            float ug = tanhf(g[2]);
            float c = ig * ug;
            if (m0 != 0.0f) c += (1.0f / (1.0f + expf(-g[3]))) * c_s[((size_t)cix[bb][0] * CB + b) * CH + hh];
            if (m1 != 0.0f) c += (1.0f / (1.0f + expf(-g[4]))) * c_s[((size_t)cix[bb][1] * CB + b) * CH + hh];
            if (m2 != 0.0f) c += (1.0f / (1.0f + expf(-g[5]))) * c_s[((size_t)cix[bb][2] * CB + b) * CH + hh];
            float h = og * tanhf(c);
            const size_t hx = ((size_t)t * CB + b) * CH + hh;
            unsigned short hb = f2bfu(h);
            h_hi[hx] = hb;
            h_lo[hx] = f2bfu(h - bfu2f(hb));
            c_s[hx] = c;
            if (t == CN - 1) out[(size_t)b * CH + hh] = h;
        }
        __threadfence();
        grid.sync();
    }
}

// ---------------------------------------------------------------------------
// Fallback (r7-verified fp32 per-step kernel).
// ---------------------------------------------------------------------------
__global__ __launch_bounds__(512) void tree_step(
    const int* __restrict__ node_ids, const int* __restrict__ children,
    const float* __restrict__ emb, const float* __restrict__ Wx_w,
    const float* __restrict__ Wx_b, const float* __restrict__ Uh_w,
    const float* __restrict__ Uh_b, float* __restrict__ h_s,
    float* __restrict__ c_s, float* __restrict__ out, const int t)
{
    const int tid = threadIdx.x;
    const int xcd  = blockIdx.x & 7;
    const int bidx = blockIdx.x >> 3;
    const int hi   = xcd * 2 + (bidx & 1);
    const int bi   = bidx >> 1;
    const int b0   = bi * 16;
    const int hh0  = hi * 16;
    const int tt   = tid >> 6;
    const int lane = tid & 63;
    const int bq   = lane >> 4;
    const int jj   = lane & 15;

    __shared__ float xh[16][1025];
    __shared__ float gred[8][16][6][16];
    __shared__ int   nid[16];
    __shared__ float msk[16][3];
    __shared__ int   cix[16][3];

    if (tid < 16) nid[tid] = node_ids[(size_t)(b0 + tid) * CN + t];
    if (tid < 48) {
        int lb = tid / 3, k = tid - lb * 3;
        int raw = children[((size_t)(b0 + lb) * CN + t) * CK + k];
        int v = raw < t;
        msk[lb][k] = v ? 1.0f : 0.0f;
        cix[lb][k] = v ? raw : 0;
    }
    __syncthreads();
    for (int i = 0; i < 32; ++i) {
        int id2 = tid + (i << 9);
        int lb  = id2 >> 10;
        int col = id2 & 1023;
        float v;
        if (col < CE) v = emb[(size_t)nid[lb] * CE + col];
        else {
            int k  = (col - CE) >> 8;
            int hc = col & 255;
            v = 0.0f;
            if (msk[lb][k] != 0.0f)
                v = h_s[((size_t)cix[lb][k] * CB + (b0 + lb)) * CH + hc];
        }
        xh[lb][col] = v;
    }
    __syncthreads();
    float acc[4][6] = {};
    {
        const float* w0p = (tt < 2)
            ? (Wx_w + (size_t)(tt * 128) * CG_ + (hh0 + jj))
            : (Uh_w + (size_t)(tt * 128 - 256) * CG_ + (hh0 + jj));
        const int colbase = tt * 128;
        #pragma unroll 4
        for (int kl = 0; kl < 128; ++kl) {
            const float* wr = w0p + (size_t)kl * CG_;
            float w0 = wr[0], w1 = wr[256], w2 = wr[512];
            float w3 = wr[768], w4 = wr[1024], w5 = wr[1280];
            int col = colbase + kl;
            #pragma unroll
            for (int r = 0; r < 4; ++r) {
                float hv = xh[bq + 4 * r][col];
                acc[r][0] += hv * w0; acc[r][1] += hv * w1; acc[r][2] += hv * w2;
                acc[r][3] += hv * w3; acc[r][4] += hv * w4; acc[r][5] += hv * w5;
            }
        }
    }
    #pragma unroll
    for (int r = 0; r < 4; ++r)
        #pragma unroll
        for (int q = 0; q < 6; ++q)
            gred[tt][bq + 4 * r][q][jj] = acc[r][q];
    __syncthreads();
    if (tid < 256) {
        const int bb = tid >> 4, j2 = tid & 15;
        const int b = b0 + bb, hh = hh0 + j2;
        float g[6];
        #pragma unroll
        for (int q = 0; q < 6; ++q) {
            float s = 0.0f;
            #pragma unroll
            for (int k = 0; k < 8; ++k) s += gred[k][bb][q][j2];
            g[q] = s;
        }
        const float m0 = msk[bb][0], m1 = msk[bb][1], m2 = msk[bb][2];
        #pragma unroll
        for (int q = 0; q < 6; ++q) {
            int gc = q * CH + hh;
            g[q] += Wx_b[gc] + m0 * Uh_b[gc] + m1 * Uh_b[CG_ + gc]
                             + m2 * Uh_b[2 * CG_ + gc];
        }
        float ig = 1.0f / (1.0f + expf(-g[0]));
        float og = 1.0f / (1.0f + expf(-g[1]));
        float ug = tanhf(g[2]);
        float c = ig * ug;
        if (m0 != 0.0f) c += (1.0f / (1.0f + expf(-g[3]))) * c_s[((size_t)cix[bb][0] * CB + b) * CH + hh];
        if (m1 != 0.0f) c += (1.0f / (1.0f + expf(-g[4]))) * c_s[((size_t)cix[bb][1] * CB + b) * CH + hh];
        if (m2 != 0.0f) c += (1.0f / (1.0f + expf(-g[5]))) * c_s[((size_t)cix[bb][2] * CB + b) * CH + hh];
        float h = og * tanhf(c);
        h_s[((size_t)t * CB + b) * CH + hh] = h;
        c_s[((size_t)t * CB + b) * CH + hh] = c;
        if (t == CN - 1) out[(size_t)b * CH + hh] = h;
    }
}

__global__ void ws_report(float* out, int n, float val) {
    int i = blockIdx.x * blockDim.x + threadIdx.x;
    if (i < n) out[i] = val;
}

// ---------------------------------------------------------------------------
extern "C" void kernel_launch(void* const* d_in, const int* in_sizes, int n_in,
                              void* d_out, int out_size, void* d_ws, size_t ws_size,
                              hipStream_t stream) {
    float* outp = (float*)d_out;

    const int expect_sizes[7] = {65536, 196608, 8192000, 393216, 1536, 1179648, 4608};
    int bad = -1;
    if (n_in != 7) bad = 7;
    else for (int i = 0; i < 7; ++i) if (in_sizes[i] != expect_sizes[i]) { bad = i; break; }
    if (bad >= 0) {
        ws_report<<<(out_size + 255) / 256, 256, 0, stream>>>(outp, out_size, 1000.0f + bad);
        return;
    }

    const int*   node_ids = (const int*)d_in[0];
    const int*   children = (const int*)d_in[1];
    const float* emb      = (const float*)d_in[2];
    const float* Wx_w     = (const float*)d_in[3];
    const float* Wx_b     = (const float*)d_in[4];
    const float* Uh_w     = (const float*)d_in[5];
    const float* Uh_b     = (const float*)d_in[6];

    const size_t w_plane  = (size_t)CG_ * KTOT * 2;   //  3,145,728 B
    const size_t h_plane  = (size_t)CN * CB * CH * 2; // 33,554,432 B (bf16)
    const size_t c_bytes  = (size_t)CN * CB * CH * 4; // 67,108,864 B
    const size_t need_mfma = 2 * w_plane + 2 * h_plane + c_bytes;  // 140,509,184 (proven r8)
    const size_t need_plain = 2 * c_bytes;                          // 134,217,728

    if (ws_size >= need_mfma) {
        char* w = (char*)d_ws;
        unsigned short* Whi = (unsigned short*)w;
        unsigned short* Wlo = (unsigned short*)(w + w_plane);
        unsigned short* hhi = (unsigned short*)(w + 2 * w_plane);
        unsigned short* hlo = (unsigned short*)(w + 2 * w_plane + h_plane);
        float*          csb = (float*)(w + 2 * w_plane + 2 * h_plane);

        prep_w<<<dim3(CG_), dim3(256), 0, stream>>>(Wx_w, Uh_w, Whi, Wlo);

        void* args[] = { (void*)&node_ids, (void*)&children, (void*)&emb,
                         (void*)&Whi, (void*)&Wlo, (void*)&Wx_b, (void*)&Uh_b,
                         (void*)&hhi, (void*)&hlo, (void*)&csb, (void*)&outp };
        hipError_t e = hipLaunchCooperativeKernel((const void*)tree_scan_mfma,
                                                  dim3(256), dim3(768), args, 0, stream);
        if (e == hipSuccess) return;
        // fall through to plain path on coop failure (reuses ws differently;
        // W-plane region unused there, h_s overlays it harmlessly)
    }
    if (ws_size >= need_plain) {
        float* h_s = (float*)d_ws;
        float* c_s = (float*)((char*)d_ws + c_bytes);
        for (int t = 0; t < CN; ++t)
            tree_step<<<dim3(256), dim3(512), 0, stream>>>(
                node_ids, children, emb, Wx_w, Wx_b, Uh_w, Uh_b,
                h_s, c_s, outp, t);
    } else {
        ws_report<<<(out_size + 255) / 256, 256, 0, stream>>>(
            outp, out_size, (float)(ws_size >> 20));
    }
}

// Round 10
// 4203.005 us; speedup vs baseline: 6.0054x; 6.0054x over previous
//
#include <hip/hip_runtime.h>
#include <hip/hip_bf16.h>

#define CB 256      // batch
#define CN 256      // nodes
#define CK 3        // children per node
#define CE 256      // embedding dim
#define CH 256      // hidden dim
#define CG_ 1536    // gates = 6*CH
#define KTOT 1024   // E + K*H
#define APAD 8
#define ASTR (KTOT + APAD)   // LDS A row stride (shorts) = 1032 (2064 B)

typedef __attribute__((ext_vector_type(8))) short short8v;          // 8 bf16
typedef __attribute__((ext_vector_type(4))) float float4v;          // MFMA C/D
typedef __attribute__((ext_vector_type(4))) unsigned int uint4v;    // 16B copy
typedef __attribute__((ext_vector_type(4))) unsigned short ushort4v;// 8B store

__device__ __forceinline__ unsigned short f2bfu(float v) {
    __hip_bfloat16 h = __float2bfloat16(v);
    return __builtin_bit_cast(unsigned short, h);
}
__device__ __forceinline__ float bfu2f(unsigned short u) {
    __hip_bfloat16 h = __builtin_bit_cast(__hip_bfloat16, u);
    return __bfloat162float(h);
}

// ---------------------------------------------------------------------------
// Prep (verified r8/r9): split virtual W = [Wx_w ; Uh_w] (1024 x 1536) into
// K-major bf16 hi/lo planes [g][k] -> B-fragments are contiguous 16B loads.
// ---------------------------------------------------------------------------
__global__ __launch_bounds__(256) void prep_w(
    const float* __restrict__ Wx_w, const float* __restrict__ Uh_w,
    unsigned short* __restrict__ Whi, unsigned short* __restrict__ Wlo)
{
    const int g = blockIdx.x;
    for (int k = threadIdx.x; k < KTOT; k += 256) {
        float w = (k < CE) ? Wx_w[(size_t)k * CG_ + g]
                           : Uh_w[(size_t)(k - CE) * CG_ + g];
        unsigned short hi = f2bfu(w);
        Whi[(size_t)g * KTOT + k] = hi;
        Wlo[(size_t)g * KTOT + k] = f2bfu(w - bfu2f(hi));
    }
}

// ---------------------------------------------------------------------------
// One tree step per launch (kernel boundary = the only sync: coop grid.sync
// measured CATASTROPHIC in r9 — device-scope fence flushes L2 every step,
// 15 MB/step HBM refetch, 100 us/step; launches keep W L2-hot).
// 256 blocks x 768 threads (12 waves). Block (bi,hi) owns 16 batch x 16 hh.
// h history stored as bf16 hi/lo planes (split at write) -> staging is pure
// 16B copies; x split in-register from fp32 emb. Waves: np=wv%3 (N-pair),
// kq=wv/3 (K-quarter, 8 k-iters). MFMA bf16x3 (verified r8/r9, absmax 1.2e-4).
// ---------------------------------------------------------------------------
__global__ __launch_bounds__(768) void tree_step_mfma(
    const int* __restrict__ node_ids,          // [B][N]
    const int* __restrict__ children,          // [B][N][K]
    const float* __restrict__ emb,             // [V][E]
    const unsigned short* __restrict__ Whi,    // [1536][1024]
    const unsigned short* __restrict__ Wlo,    // [1536][1024]
    const float* __restrict__ Wx_b,            // [G]
    const float* __restrict__ Uh_b,            // [K][G]
    unsigned short* __restrict__ h_hi,         // [N][B][H] bf16 hi plane
    unsigned short* __restrict__ h_lo,         // [N][B][H] bf16 lo plane
    float* __restrict__ c_s,                   // [N][B][H] f32
    float* __restrict__ out,                   // [B][H] f32
    const int t)
{
    const int tid = threadIdx.x;

    const int xcd  = blockIdx.x & 7;
    const int bidx = blockIdx.x >> 3;
    const int hi   = xcd * 2 + (bidx & 1);
    const int bi   = bidx >> 1;
    const int b0   = bi * 16;
    const int hh0  = hi * 16;

    __shared__ unsigned short Ahi[16][ASTR];   // 33,024 B
    __shared__ unsigned short Alo[16][ASTR];   // 33,024 B
    __shared__ float part[4][6][16][16];       // 24,576 B  [kq][q][bb][jj]
    __shared__ int   nid[16];
    __shared__ float msk[16][3];
    __shared__ int   cix[16][3];

    const int wv    = tid >> 6;                // 0..11
    const int l     = tid & 63;
    const int np    = wv % 3;                  // N-pair
    const int kq    = wv / 3;                  // K-quarter
    const int lan15 = l & 15;
    const int k8    = (l >> 4) * 8;

    if (tid < 16) nid[tid] = node_ids[(size_t)(b0 + tid) * CN + t];
    if (tid < 48) {
        int lb = tid / 3, k = tid - lb * 3;
        int raw = children[((size_t)(b0 + lb) * CN + t) * CK + k];
        int v = raw < t;
        msk[lb][k] = v ? 1.0f : 0.0f;
        cix[lb][k] = v ? raw : 0;
    }
    __syncthreads();

    // stage x: 16 rows x 64 float4 chunks; split hi/lo in-register
    for (int idx = tid; idx < 1024; idx += 768) {
        int lb = idx >> 6, c4 = idx & 63;
        float4v v = *(const float4v*)(emb + (size_t)nid[lb] * CE + c4 * 4);
        ushort4v h4, l4;
        #pragma unroll
        for (int j = 0; j < 4; ++j) {
            unsigned short hb = f2bfu(v[j]);
            h4[j] = hb;
            l4[j] = f2bfu(v[j] - bfu2f(hb));
        }
        *(ushort4v*)&Ahi[lb][c4 * 4] = h4;
        *(ushort4v*)&Alo[lb][c4 * 4] = l4;
    }
    // stage h: 48 rows x (32 hi + 32 lo) 16B chunks = 3072 copies
    for (int idx = tid; idx < 3072; idx += 768) {
        int r  = idx >> 6;                 // 0..47
        int c  = idx & 63;
        int pl = c >> 5;                   // 0=hi, 1=lo
        int ch = c & 31;                   // 16B chunk in row
        int lb = r / 3, k = r - lb * 3;
        uint4v val = (uint4v){0u, 0u, 0u, 0u};
        if (msk[lb][k] != 0.0f) {
            const unsigned short* src = (pl ? h_lo : h_hi)
                + ((size_t)cix[lb][k] * CB + (b0 + lb)) * CH + ch * 8;
            val = *(const uint4v*)src;
        }
        unsigned short* dst = (pl ? &Alo[lb][CE + k * CH + ch * 8]
                                  : &Ahi[lb][CE + k * CH + ch * 8]);
        *(uint4v*)dst = val;
    }
    __syncthreads();

    // MFMA bf16x3: 8 k-iters per wave, 2 q-tiles, 3 chains
    {
        float4v acc[2][3];
        #pragma unroll
        for (int a = 0; a < 2; ++a)
            #pragma unroll
            for (int b = 0; b < 3; ++b)
                acc[a][b] = (float4v){0.f, 0.f, 0.f, 0.f};

        #pragma unroll
        for (int ci = 0; ci < 8; ++ci) {
            const int kb = (kq * 8 + ci) * 32 + k8;
            short8v ahi = *(const short8v*)&Ahi[lan15][kb];
            short8v alo = *(const short8v*)&Alo[lan15][kb];
            #pragma unroll
            for (int t2 = 0; t2 < 2; ++t2) {
                const size_t gcol = (size_t)((np * 2 + t2) * CH + hh0 + lan15);
                short8v bhi = *(const short8v*)(Whi + gcol * KTOT + kb);
                short8v blo = *(const short8v*)(Wlo + gcol * KTOT + kb);
                acc[t2][0] = __builtin_amdgcn_mfma_f32_16x16x32_bf16(ahi, bhi, acc[t2][0], 0, 0, 0);
                acc[t2][1] = __builtin_amdgcn_mfma_f32_16x16x32_bf16(ahi, blo, acc[t2][1], 0, 0, 0);
                acc[t2][2] = __builtin_amdgcn_mfma_f32_16x16x32_bf16(alo, bhi, acc[t2][2], 0, 0, 0);
            }
        }
        #pragma unroll
        for (int t2 = 0; t2 < 2; ++t2)
            #pragma unroll
            for (int r = 0; r < 4; ++r)
                part[kq][np * 2 + t2][(l >> 4) * 4 + r][lan15] =
                    acc[t2][0][r] + acc[t2][1][r] + acc[t2][2][r];
    }
    __syncthreads();

    // cell phase (r7-verified math; h written pre-split)
    if (tid < 256) {
        const int bb = tid >> 4, j2 = tid & 15;
        const int b = b0 + bb, hh = hh0 + j2;
        const float m0 = msk[bb][0], m1 = msk[bb][1], m2 = msk[bb][2];
        float g[6];
        #pragma unroll
        for (int q = 0; q < 6; ++q) {
            int gc = q * CH + hh;
            g[q] = part[0][q][bb][j2] + part[1][q][bb][j2]
                 + part[2][q][bb][j2] + part[3][q][bb][j2]
                 + Wx_b[gc] + m0 * Uh_b[gc] + m1 * Uh_b[CG_ + gc]
                            + m2 * Uh_b[2 * CG_ + gc];
        }
        float ig = 1.0f / (1.0f + expf(-g[0]));
        float og = 1.0f / (1.0f + expf(-g[1]));
        float ug = tanhf(g[2]);
        float c = ig * ug;
        if (m0 != 0.0f) c += (1.0f / (1.0f + expf(-g[3]))) * c_s[((size_t)cix[bb][0] * CB + b) * CH + hh];
        if (m1 != 0.0f) c += (1.0f / (1.0f + expf(-g[4]))) * c_s[((size_t)cix[bb][1] * CB + b) * CH + hh];
        if (m2 != 0.0f) c += (1.0f / (1.0f + expf(-g[5]))) * c_s[((size_t)cix[bb][2] * CB + b) * CH + hh];
        float h = og * tanhf(c);
        const size_t hx = ((size_t)t * CB + b) * CH + hh;
        unsigned short hb = f2bfu(h);
        h_hi[hx] = hb;
        h_lo[hx] = f2bfu(h - bfu2f(hb));
        c_s[hx] = c;
        if (t == CN - 1) out[(size_t)b * CH + hh] = h;
    }
}

// ---------------------------------------------------------------------------
// Fallback (r7-verified fp32 per-step kernel), used only if ws too small.
// ---------------------------------------------------------------------------
__global__ __launch_bounds__(512) void tree_step(
    const int* __restrict__ node_ids, const int* __restrict__ children,
    const float* __restrict__ emb, const float* __restrict__ Wx_w,
    const float* __restrict__ Wx_b, const float* __restrict__ Uh_w,
    const float* __restrict__ Uh_b, float* __restrict__ h_s,
    float* __restrict__ c_s, float* __restrict__ out, const int t)
{
    const int tid = threadIdx.x;
    const int xcd  = blockIdx.x & 7;
    const int bidx = blockIdx.x >> 3;
    const int hi   = xcd * 2 + (bidx & 1);
    const int bi   = bidx >> 1;
    const int b0   = bi * 16;
    const int hh0  = hi * 16;
    const int tt   = tid >> 6;
    const int lane = tid & 63;
    const int bq   = lane >> 4;
    const int jj   = lane & 15;

    __shared__ float xh[16][1025];
    __shared__ float gred[8][16][6][16];
    __shared__ int   nid[16];
    __shared__ float msk[16][3];
    __shared__ int   cix[16][3];

    if (tid < 16) nid[tid] = node_ids[(size_t)(b0 + tid) * CN + t];
    if (tid < 48) {
        int lb = tid / 3, k = tid - lb * 3;
        int raw = children[((size_t)(b0 + lb) * CN + t) * CK + k];
        int v = raw < t;
        msk[lb][k] = v ? 1.0f : 0.0f;
        cix[lb][k] = v ? raw : 0;
    }
    __syncthreads();
    for (int i = 0; i < 32; ++i) {
        int id2 = tid + (i << 9);
        int lb  = id2 >> 10;
        int col = id2 & 1023;
        float v;
        if (col < CE) v = emb[(size_t)nid[lb] * CE + col];
        else {
            int k  = (col - CE) >> 8;
            int hc = col & 255;
            v = 0.0f;
            if (msk[lb][k] != 0.0f)
                v = h_s[((size_t)cix[lb][k] * CB + (b0 + lb)) * CH + hc];
        }
        xh[lb][col] = v;
    }
    __syncthreads();
    float acc[4][6] = {};
    {
        const float* w0p = (tt < 2)
            ? (Wx_w + (size_t)(tt * 128) * CG_ + (hh0 + jj))
            : (Uh_w + (size_t)(tt * 128 - 256) * CG_ + (hh0 + jj));
        const int colbase = tt * 128;
        #pragma unroll 4
        for (int kl = 0; kl < 128; ++kl) {
            const float* wr = w0p + (size_t)kl * CG_;
            float w0 = wr[0], w1 = wr[256], w2 = wr[512];
            float w3 = wr[768], w4 = wr[1024], w5 = wr[1280];
            int col = colbase + kl;
            #pragma unroll
            for (int r = 0; r < 4; ++r) {
                float hv = xh[bq + 4 * r][col];
                acc[r][0] += hv * w0; acc[r][1] += hv * w1; acc[r][2] += hv * w2;
                acc[r][3] += hv * w3; acc[r][4] += hv * w4; acc[r][5] += hv * w5;
            }
        }
    }
    #pragma unroll
    for (int r = 0; r < 4; ++r)
        #pragma unroll
        for (int q = 0; q < 6; ++q)
            gred[tt][bq + 4 * r][q][jj] = acc[r][q];
    __syncthreads();
    if (tid < 256) {
        const int bb = tid >> 4, j2 = tid & 15;
        const int b = b0 + bb, hh = hh0 + j2;
        float g[6];
        #pragma unroll
        for (int q = 0; q < 6; ++q) {
            float s = 0.0f;
            #pragma unroll
            for (int k = 0; k < 8; ++k) s += gred[k][bb][q][j2];
            g[q] = s;
        }
        const float m0 = msk[bb][0], m1 = msk[bb][1], m2 = msk[bb][2];
        #pragma unroll
        for (int q = 0; q < 6; ++q) {
            int gc = q * CH + hh;
            g[q] += Wx_b[gc] + m0 * Uh_b[gc] + m1 * Uh_b[CG_ + gc]
                             + m2 * Uh_b[2 * CG_ + gc];
        }
        float ig = 1.0f / (1.0f + expf(-g[0]));
        float og = 1.0f / (1.0f + expf(-g[1]));
        float ug = tanhf(g[2]);
        float c = ig * ug;
        if (m0 != 0.0f) c += (1.0f / (1.0f + expf(-g[3]))) * c_s[((size_t)cix[bb][0] * CB + b) * CH + hh];
        if (m1 != 0.0f) c += (1.0f / (1.0f + expf(-g[4]))) * c_s[((size_t)cix[bb][1] * CB + b) * CH + hh];
        if (m2 != 0.0f) c += (1.0f / (1.0f + expf(-g[5]))) * c_s[((size_t)cix[bb][2] * CB + b) * CH + hh];
        float h = og * tanhf(c);
        h_s[((size_t)t * CB + b) * CH + hh] = h;
        c_s[((size_t)t * CB + b) * CH + hh] = c;
        if (t == CN - 1) out[(size_t)b * CH + hh] = h;
    }
}

__global__ void ws_report(float* out, int n, float val) {
    int i = blockIdx.x * blockDim.x + threadIdx.x;
    if (i < n) out[i] = val;
}

// ---------------------------------------------------------------------------
extern "C" void kernel_launch(void* const* d_in, const int* in_sizes, int n_in,
                              void* d_out, int out_size, void* d_ws, size_t ws_size,
                              hipStream_t stream) {
    float* outp = (float*)d_out;

    const int expect_sizes[7] = {65536, 196608, 8192000, 393216, 1536, 1179648, 4608};
    int bad = -1;
    if (n_in != 7) bad = 7;
    else for (int i = 0; i < 7; ++i) if (in_sizes[i] != expect_sizes[i]) { bad = i; break; }
    if (bad >= 0) {
        ws_report<<<(out_size + 255) / 256, 256, 0, stream>>>(outp, out_size, 1000.0f + bad);
        return;
    }

    const int*   node_ids = (const int*)d_in[0];
    const int*   children = (const int*)d_in[1];
    const float* emb      = (const float*)d_in[2];
    const float* Wx_w     = (const float*)d_in[3];
    const float* Wx_b     = (const float*)d_in[4];
    const float* Uh_w     = (const float*)d_in[5];
    const float* Uh_b     = (const float*)d_in[6];

    const size_t w_plane  = (size_t)CG_ * KTOT * 2;   //  3,145,728 B
    const size_t h_plane  = (size_t)CN * CB * CH * 2; // 33,554,432 B (bf16)
    const size_t c_bytes  = (size_t)CN * CB * CH * 4; // 67,108,864 B
    const size_t need_mfma = 2 * w_plane + 2 * h_plane + c_bytes;  // 140,509,184 (proven r8/r9)
    const size_t need_plain = 2 * c_bytes;                          // 134,217,728

    if (ws_size >= need_mfma) {
        char* w = (char*)d_ws;
        unsigned short* Whi = (unsigned short*)w;
        unsigned short* Wlo = (unsigned short*)(w + w_plane);
        unsigned short* hhi = (unsigned short*)(w + 2 * w_plane);
        unsigned short* hlo = (unsigned short*)(w + 2 * w_plane + h_plane);
        float*          csb = (float*)(w + 2 * w_plane + 2 * h_plane);

        prep_w<<<dim3(CG_), dim3(256), 0, stream>>>(Wx_w, Uh_w, Whi, Wlo);
        for (int t = 0; t < CN; ++t)
            tree_step_mfma<<<dim3(256), dim3(768), 0, stream>>>(
                node_ids, children, emb, Whi, Wlo, Wx_b, Uh_b,
                hhi, hlo, csb, outp, t);
    } else if (ws_size >= need_plain) {
        float* h_s = (float*)d_ws;
        float* c_s = (float*)((char*)d_ws + c_bytes);
        for (int t = 0; t < CN; ++t)
            tree_step<<<dim3(256), dim3(512), 0, stream>>>(
                node_ids, children, emb, Wx_w, Wx_b, Uh_w, Uh_b,
                h_s, c_s, outp, t);
    } else {
        ws_report<<<(out_size + 255) / 256, 256, 0, stream>>>(
            outp, out_size, (float)(ws_size >> 20));
    }
}